// Round 19
// baseline (305.182 us; speedup 1.0000x reference)
//
#include <hip/hip_runtime.h>
#include <hip/hip_bf16.h>
#include <cstdint>

#define S_SEQ   2048
#define HID     4096
#define NQH     32
#define NKVH    8
#define DH      128
#define QKV_LD  6144      // (32+16)*128
#define SCALE_F 0.08838834764831845f
// softmax in log2 domain: s' = s * SCALE * log2(e)
#define C2F (0.08838834764831845f * 1.4426950408889634f)

using f32x4  = __attribute__((ext_vector_type(4))) float;
using f32x16 = __attribute__((ext_vector_type(16))) float;
using bf16x8 = __attribute__((ext_vector_type(8))) __bf16;
using u32x2  = __attribute__((ext_vector_type(2))) unsigned;

#define GLOAD_LDS16(gp, lp)                                                   \
  __builtin_amdgcn_global_load_lds(                                           \
      (__attribute__((address_space(1))) const void*)(gp),                    \
      (__attribute__((address_space(3))) void*)(lp), 16, 0, 0)

__device__ __forceinline__ unsigned short f2bf_bits(float f) {
  __hip_bfloat16 b = __float2bfloat16(f);
  return __builtin_bit_cast(unsigned short, b);
}

// permlane32_swap: X[32..63] <-> Y[0..31].
__device__ __forceinline__ void plswap(unsigned& x, unsigned& y) {
  u32x2 r = __builtin_amdgcn_permlane32_swap(x, y, false, false);
  x = r[0];
  y = r[1];
}
// value of the partner lane (l ^ 32)
__device__ __forceinline__ float xhalf(float v, int hiP) {
  unsigned u = __builtin_bit_cast(unsigned, v);
  u32x2 r = __builtin_amdgcn_permlane32_swap(u, u, false, false);
  return __builtin_bit_cast(float, hiP ? r[0] : r[1]);
}

// ---------------------------------------------------------------------------
// merged f32 -> bf16 conversion for hs + wqkv (single kernel, fewer tails)
// ---------------------------------------------------------------------------
__global__ void cvt2_kernel(const float* __restrict__ hs,
                            __hip_bfloat16* __restrict__ hsb,
                            const float* __restrict__ wq,
                            __hip_bfloat16* __restrict__ wqb) {
  const int NHS = (S_SEQ * HID) / 4;     // 2,097,152 float4
  const int NWQ = (QKV_LD * HID) / 4;    // 6,291,456 float4
  int i = blockIdx.x * blockDim.x + threadIdx.x;
  int stride = gridDim.x * blockDim.x;
  for (int e = i; e < NHS + NWQ; e += stride) {
    const float4* src;
    ushort4* dst;
    int idx;
    if (e < NHS) {
      src = (const float4*)hs; dst = (ushort4*)hsb; idx = e;
    } else {
      src = (const float4*)wq; dst = (ushort4*)wqb; idx = e - NHS;
    }
    float4 v = src[idx];
    ushort4 u;
    u.x = f2bf_bits(v.x); u.y = f2bf_bits(v.y);
    u.z = f2bf_bits(v.z); u.w = f2bf_bits(v.w);
    dst[idx] = u;
  }
}

// ---------------------------------------------------------------------------
// GEMM: C[M,N] = A[M,K] * B[N,K]^T   (both bf16, B^T layout)
// Tile (MF*32) x 256, BK=64, 8 waves, 512 threads. m201-style two-barrier
// phases (m-half x ks), LDS double-buffered:
//  per phase: { ds_read this phase's frags; issue ONE stage-group (t+1);
//               s_barrier;  <- read latency absorbed here
//               lgkmcnt(0)+sched_barrier;
//               setprio(1) 16-MFMA cluster setprio(0);
//               [counted vmcnt at phB/phD]; s_barrier }
//  - bfr[4] read in phA/phC, held across the ks's two phases; af re-read
//    per phase (total LDS reads unchanged: 24 b128 / K-tile)
//  - groups g0=A-ks0, g1=B-ks0, g2=A-ks1, g3=B-ks1; vmcnt(4)/(3) forces
//    exactly the two groups the next two phases need; vmcnt(0) last tile
//  - slot swizzle (slot ^= (row>>1)&3) linear-dest + inverse-permuted source
//  - bijective XCD swizzle; column-major wgid decode (B-panel L2 sharing)
//  - FUSE: grid-x blocks >= nbx_main run the wo f32->bf16 convert
// ---------------------------------------------------------------------------
template <bool OUT_BF16, int MF, bool FUSE>
__global__ __launch_bounds__(512) void gemm_bt_kernel(
    const __hip_bfloat16* __restrict__ A, const __hip_bfloat16* __restrict__ B,
    void* __restrict__ Cv, int M, int N, int K, int nbx_main,
    const float* __restrict__ csrc, __hip_bfloat16* __restrict__ cdst,
    int cn4) {
  extern __shared__ __hip_bfloat16 sAB[];
  constexpr int A_BUF = MF * 2048;       // elements of A per buffer
  constexpr int A_KS  = MF * 1024;       // elements per k-slice of A
  constexpr int BUFSZ = A_BUF + 16384;   // + B (256 rows x 32 el) x 2 slices
  constexpr int MH = MF / 2;             // m-frags per phase
  const int tid = threadIdx.x;

  if (FUSE) {
    if ((int)blockIdx.x >= nbx_main) {
      const int nb = gridDim.x - nbx_main;
      const int cid = ((int)blockIdx.x - nbx_main) + (int)blockIdx.y * nb;
      const int stride = nb * gridDim.y * 512;
      for (int e = cid * 512 + tid; e < cn4; e += stride) {
        float4 v = ((const float4*)csrc)[e];
        ushort4 u;
        u.x = f2bf_bits(v.x); u.y = f2bf_bits(v.y);
        u.z = f2bf_bits(v.z); u.w = f2bf_bits(v.w);
        ((ushort4*)cdst)[e] = u;
      }
      return;
    }
  }

  const int w = tid >> 6, l = tid & 63;
  const int wm = w >> 2, wn = w & 3;
  const int lr = l & 15;

  const int nbx = nbx_main;
  const int gdy = gridDim.y;
  const int nwg = nbx * gdy;
  int wgid = blockIdx.y * nbx + blockIdx.x;
  wgid = (wgid & 7) * (nwg >> 3) + (wgid >> 3);  // XCD chunking
  const int bx = wgid / gdy;   // column-major: chunk shares B panels
  const int by = wgid % gdy;
  const int brow = by * (MF * 32);
  const int bcol = bx * 256;

  f32x4 acc[MF][4];
#pragma unroll
  for (int m = 0; m < MF; m++)
#pragma unroll
    for (int n = 0; n < 4; n++) acc[m][n] = (f32x4){0.f, 0.f, 0.f, 0.f};

  const int r0 = tid >> 2;                                  // 0..127
  const int c0s = (((tid & 3) ^ ((tid >> 3) & 3)) << 3);    // elements
  const __hip_bfloat16* Ag = A + (size_t)(brow + r0) * K + c0s;
  const __hip_bfloat16* Bg = B + (size_t)(bcol + r0) * K + c0s;
  const int ldst = tid * 8;

  const int sw8 = (((l >> 4) ^ ((lr >> 1) & 3)) << 3);

#define STG_A(BUF, K0, KS, RB)                                                \
  GLOAD_LDS16(Ag + (K0) + (KS) * 32 + (size_t)((RB) * 128) * K,               \
              sAB + (BUF) * BUFSZ + (KS) * A_KS + (RB) * 4096 + ldst)
#define STG_B(BUF, K0, KS, RB)                                                \
  GLOAD_LDS16(Bg + (K0) + (KS) * 32 + (size_t)((RB) * 128) * K,               \
              sAB + (BUF) * BUFSZ + A_BUF + (KS) * 8192 + (RB) * 4096 + ldst)
#define STG_G0(BUF, K0)                                                       \
  {                                                                           \
    STG_A(BUF, K0, 0, 0);                                                     \
    if constexpr (MF == 8) STG_A(BUF, K0, 0, 1);                              \
  }
#define STG_G1(BUF, K0) { STG_B(BUF, K0, 0, 0); STG_B(BUF, K0, 0, 1); }
#define STG_G2(BUF, K0)                                                       \
  {                                                                           \
    STG_A(BUF, K0, 1, 0);                                                     \
    if constexpr (MF == 8) STG_A(BUF, K0, 1, 1);                              \
  }
#define STG_G3(BUF, K0) { STG_B(BUF, K0, 1, 0); STG_B(BUF, K0, 1, 1); }

#define WAIT_L()                                                              \
  {                                                                           \
    if constexpr (MF == 8)                                                    \
      asm volatile("s_waitcnt vmcnt(4)" ::: "memory");                        \
    else                                                                      \
      asm volatile("s_waitcnt vmcnt(3)" ::: "memory");                        \
  }
// barrier #1 of a phase: pin reads+stage before it
#define BAR1()                                                                \
  {                                                                           \
    __builtin_amdgcn_sched_barrier(0);                                        \
    __builtin_amdgcn_s_barrier();                                             \
  }
#define LGKM()                                                                \
  {                                                                           \
    asm volatile("s_waitcnt lgkmcnt(0)" ::: "memory");                        \
    __builtin_amdgcn_sched_barrier(0);                                        \
  }
// MFMA cluster: m-half MHI (rows MHI*MH..+MH) x all 4 n
#define CLUSTER(MHI)                                                          \
  {                                                                           \
    __builtin_amdgcn_s_setprio(1);                                            \
    _Pragma("unroll") for (int mm = 0; mm < MH; mm++)                         \
        _Pragma("unroll") for (int n = 0; n < 4; n++)                         \
        acc[(MHI)*MH + mm][n] = __builtin_amdgcn_mfma_f32_16x16x32_bf16(      \
            af[mm], bfr[n], acc[(MHI)*MH + mm][n], 0, 0, 0);                  \
    __builtin_amdgcn_s_setprio(0);                                            \
  }
#define RD_AF(BASE, MHI)                                                      \
  _Pragma("unroll") for (int mm = 0; mm < MH; mm++) af[mm] =                  \
      *(const bf16x8*)&(BASE)[(wm * MF * 16 + ((MHI)*MH + mm) * 16 + lr) * 32 \
                              + sw8];
#define RD_BF(BASE)                                                           \
  _Pragma("unroll") for (int n = 0; n < 4; n++) bfr[n] =                      \
      *(const bf16x8*)&(BASE)[(wn * 64 + n * 16 + lr) * 32 + sw8];

  const int nt = K >> 6;  // 64 K-tiles
  // prologue: all 4 groups of tile 0; wait g0,g1 (leaves g2,g3 in flight)
  STG_G0(0, 0); STG_G1(0, 0); STG_G2(0, 0); STG_G3(0, 0);
  WAIT_L();
  __builtin_amdgcn_s_barrier();

  for (int t = 0; t < nt; ++t) {
    const int buf = t & 1, nb2 = buf ^ 1;
    const int k1 = (t + 1) << 6;
    const bool hn = (t + 1) < nt;
    const __hip_bfloat16* ab = sAB + buf * BUFSZ;
    const __hip_bfloat16* bb = ab + A_BUF;
    const __hip_bfloat16* ab1 = ab + A_KS;
    const __hip_bfloat16* bb1 = bb + 8192;
    bf16x8 af[MH], bfr[4];

    // ---- phA: ks0, m-half 0 ----
    RD_BF(bb);
    RD_AF(ab, 0);
    if (hn) STG_G0(nb2, k1);
    BAR1();
    LGKM();
    CLUSTER(0);
    __builtin_amdgcn_s_barrier();

    // ---- phB: ks0, m-half 1 (bfr held) ----
    RD_AF(ab, 1);
    if (hn) STG_G1(nb2, k1);
    BAR1();
    LGKM();
    CLUSTER(1);
    if (hn) {
      WAIT_L();   // forces g2,g3 of tile t (leaves g0',g1')
    } else {
      asm volatile("s_waitcnt vmcnt(0)" ::: "memory");
    }
    __builtin_amdgcn_s_barrier();

    // ---- phC: ks1, m-half 0 ----
    RD_BF(bb1);
    RD_AF(ab1, 0);
    if (hn) STG_G2(nb2, k1);
    BAR1();
    LGKM();
    CLUSTER(0);
    __builtin_amdgcn_s_barrier();

    // ---- phD: ks1, m-half 1 (bfr held) ----
    RD_AF(ab1, 1);
    if (hn) STG_G3(nb2, k1);
    BAR1();
    LGKM();
    CLUSTER(1);
    if (hn) {
      WAIT_L();   // forces g0',g1' of tile t+1 (leaves g2',g3')
    }
    __builtin_amdgcn_s_barrier();
  }
#undef STG_A
#undef STG_B
#undef STG_G0
#undef STG_G1
#undef STG_G2
#undef STG_G3
#undef WAIT_L
#undef BAR1
#undef LGKM
#undef CLUSTER
#undef RD_AF
#undef RD_BF

  const int jr = (l >> 4) << 2;
  if (OUT_BF16) {
    __hip_bfloat16* C = (__hip_bfloat16*)Cv;
#pragma unroll
    for (int m = 0; m < MF; m++)
#pragma unroll
      for (int n = 0; n < 4; n++)
#pragma unroll
        for (int j = 0; j < 4; j++) {
          size_t row = brow + wm * MF * 16 + m * 16 + jr + j;
          size_t col = bcol + wn * 64 + n * 16 + lr;
          C[row * N + col] = __float2bfloat16(acc[m][n][j]);
        }
  } else {
    float* C = (float*)Cv;
#pragma unroll
    for (int m = 0; m < MF; m++)
#pragma unroll
      for (int n = 0; n < 4; n++)
#pragma unroll
        for (int j = 0; j < 4; j++) {
          size_t row = brow + wm * MF * 16 + m * 16 + jr + j;
          size_t col = bcol + wn * 64 + n * 16 + lr;
          C[row * N + col] = acc[m][n][j];
        }
  }
}

// ---------------------------------------------------------------------------
// RoPE (neox) in-place on Q only (heads 0..31); K rope fused into packkv.
// ---------------------------------------------------------------------------
__global__ void ropeq_kernel(__hip_bfloat16* __restrict__ QKV,
                             const int* __restrict__ pos) {
  int idx = blockIdx.x * blockDim.x + threadIdx.x;  // S*32*64 total
  int d = idx & 63;
  int head = (idx >> 6) & 31;
  int s = idx >> 11;
  float p = (float)pos[s];
  float inv = exp2f(-(float)d * 0.2076205059304297f);
  float fr = p * inv;
  float sn, cs;
  sincosf(fr, &sn, &cs);
  size_t base = (size_t)s * QKV_LD + head * 128 + d;
  float x1 = __bfloat162float(QKV[base]);
  float x2 = __bfloat162float(QKV[base + 64]);
  QKV[base]      = __float2bfloat16(x1 * cs - x2 * sn);
  QKV[base + 64] = __float2bfloat16(x2 * cs + x1 * sn);
}

// ---------------------------------------------------------------------------
// Pack K (with fused rope) and V into fragment-ordered buffers for attn.
// ---------------------------------------------------------------------------
__global__ void packkv_kernel(const __hip_bfloat16* __restrict__ QKV,
                              const int* __restrict__ pos,
                              __hip_bfloat16* __restrict__ Kf,
                              __hip_bfloat16* __restrict__ Vf) {
  int o = blockIdx.x * blockDim.x + threadIdx.x;  // 2 * 2^18 chunks
  const int lane = o & 63;
  const int slot = (o >> 6) & 7;
  const int t    = (o >> 9) & 63;
  const int kvh  = (o >> 15) & 7;
  const int off8 = (o & 0x3FFFF) * 8;
  if (o < (1 << 18)) {
    const int s  = t * 32 + (lane & 31);
    const int d0 = slot * 16 + (lane >> 5) * 8;
    const __hip_bfloat16* kb = QKV + (size_t)s * QKV_LD + 4096 + kvh * DH;
    bf16x8 own = *(const bf16x8*)(kb + d0);
    bf16x8 prt = *(const bf16x8*)(kb + (d0 ^ 64));
    float p = (float)pos[s];
    bf16x8 outv;
#pragma unroll
    for (int j = 0; j < 8; j++) {
      float f = (float)((d0 & 63) + j);
      float inv = exp2f(-f * 0.2076205059304297f);
      float sn, cs;
      sincosf(p * inv, &sn, &cs);
      float a = (float)own[j], b = (float)prt[j];
      outv[j] = (__bf16)((d0 < 64) ? (a * cs - b * sn) : (a * cs + b * sn));
    }
    *(bf16x8*)(Kf + off8) = outv;
  } else {
    const int s0 = t * 32 + (slot & 1) * 16 + (lane >> 5) * 8;
    const int d  = (slot >> 1) * 32 + (lane & 31);
    const __hip_bfloat16* src = QKV + (size_t)s0 * QKV_LD + 5120 + kvh * DH + d;
    ushort4 a, b;
    a.x = __builtin_bit_cast(unsigned short, src[0 * QKV_LD]);
    a.y = __builtin_bit_cast(unsigned short, src[1 * QKV_LD]);
    a.z = __builtin_bit_cast(unsigned short, src[2 * QKV_LD]);
    a.w = __builtin_bit_cast(unsigned short, src[3 * QKV_LD]);
    b.x = __builtin_bit_cast(unsigned short, src[4 * QKV_LD]);
    b.y = __builtin_bit_cast(unsigned short, src[5 * QKV_LD]);
    b.z = __builtin_bit_cast(unsigned short, src[6 * QKV_LD]);
    b.w = __builtin_bit_cast(unsigned short, src[7 * QKV_LD]);
    *(ushort4*)(Vf + off8)     = a;
    *(ushort4*)(Vf + off8 + 4) = b;
  }
}

// ---------------------------------------------------------------------------
// Causal GQA flash attention (unchanged): swapped-QK 32x32 + split-KV x2.
// ---------------------------------------------------------------------------
__global__ __launch_bounds__(256, 2) void attn_kernel(
    const __hip_bfloat16* __restrict__ QKV, const __hip_bfloat16* __restrict__ Kf,
    const __hip_bfloat16* __restrict__ Vf, __hip_bfloat16* __restrict__ O) {
  __shared__ float Ms[2][64][67];
  const int tid = threadIdx.x;
  const int w = tid >> 6, l = tid & 63;
  const int l31 = l & 31;
  const int hiP = l >> 5;
  const int bid = blockIdx.x;
  const int kvh = bid & 7;
  const int hp = (bid >> 3) & 1;
  const int qt = 63 - (bid >> 4);
  const int half = w >> 1;
  const int h = kvh * 4 + hp * 2 + (w & 1);
  const int qwb = qt * 32;
  const int qg = qwb + l31;

  const __hip_bfloat16* Qp  = QKV + (size_t)h * DH;
  const __hip_bfloat16* Kfp = Kf + (size_t)kvh * 262144 + l * 8;
  const __hip_bfloat16* Vfp = Vf + (size_t)kvh * 262144 + l * 8;

  bf16x8 qf[8];
  {
    const __hip_bfloat16* qrow = Qp + (size_t)(qwb + l31) * QKV_LD + hiP * 8;
#pragma unroll
    for (int ks = 0; ks < 8; ks++) qf[ks] = *(const bf16x8*)(qrow + ks * 16);
  }

  f32x16 oacc[4];
#pragma unroll
  for (int db = 0; db < 4; db++)
#pragma unroll
    for (int r = 0; r < 16; r++) oacc[db][r] = 0.f;
  float m = -1e30f, lsum = 0.f;

#define COMPUTE_TILE(KB, MASKED)                                               \
  {                                                                            \
    const int kb_ = (KB);                                                      \
    const int toff_ = (kb_ >> 5) * 4096;                                       \
    f32x16 sacc;                                                               \
    _Pragma("unroll") for (int r = 0; r < 16; r++) sacc[r] = 0.f;              \
    {                                                                          \
      bf16x8 kf[8];                                                            \
      _Pragma("unroll") for (int ks = 0; ks < 8; ks++) kf[ks] =                \
          *(const bf16x8*)(Kfp + toff_ + ks * 512);                            \
      _Pragma("unroll") for (int ks = 0; ks < 8; ks++) sacc =                  \
          __builtin_amdgcn_mfma_f32_32x32x16_bf16(kf[ks], qf[ks], sacc, 0, 0,  \
                                                  0);                          \
    }                                                                          \
    bf16x8 vf[4][2];                                                           \
    _Pragma("unroll") for (int db = 0; db < 4; db++)                           \
        _Pragma("unroll") for (int k2 = 0; k2 < 2; k2++) vf[db][k2] =          \
        *(const bf16x8*)(Vfp + toff_ + (db * 2 + k2) * 512);                   \
    float s[16];                                                               \
    _Pragma("unroll") for (int r = 0; r < 16; r++) s[r] = sacc[r] * C2F;       \
    if (MASKED) {                                                              \
      _Pragma("unroll") for (int r = 0; r < 16; r++) {                         \
        const int kvg = kb_ + (r & 3) + 8 * (r >> 2) + 4 * hiP;                \
        s[r] = (kvg <= qg) ? s[r] : -1e30f;                                    \
      }                                                                        \
    }                                                                          \
    float m0 = fmaxf(fmaxf(s[0], s[1]), fmaxf(s[2], s[3]));                    \
    float m1 = fmaxf(fmaxf(s[4], s[5]), fmaxf(s[6], s[7]));                    \
    float m2 = fmaxf(fmaxf(s[8], s[9]), fmaxf(s[10], s[11]));                  \
    float m3 = fmaxf(fmaxf(s[12], s[13]), fmaxf(s[14], s[15]));                \
    float rmax = fmaxf(fmaxf(m0, m1), fmaxf(m2, m3));                          \
    rmax = fmaxf(rmax, xhalf(rmax, hiP));                                      \
    if (__any(rmax - m > 8.0f)) {                                              \
      float mn = fmaxf(m, rmax);                                               \
      float sc = __builtin_amdgcn_exp2f(m - mn);                               \
      lsum *= sc;                                                              \
      _Pragma("unroll") for (int db = 0; db < 4; db++)                         \
          _Pragma("unroll") for (int r = 0; r < 16; r++) oacc[db][r] *= sc;    \
      m = mn;                                                                  \
    }                                                                          \
    float p[16];                                                               \
    _Pragma("unroll") for (int r = 0; r < 16; r++) p[r] =                      \
        __builtin_amdgcn_exp2f(s[r] - m);                                      \
    float rs = ((p[0] + p[1]) + (p[2] + p[3])) +                               \
               ((p[4] + p[5]) + (p[6] + p[7])) +                               \
               ((p[8] + p[9]) + (p[10] + p[11])) +                             \
               ((p[12] + p[13]) + (p[14] + p[15]));                            \
    lsum += rs + xhalf(rs, hiP);                                               \
    unsigned Wp[8];                                                            \
    _Pragma("unroll") for (int i = 0; i < 8; i++) Wp[i] =                      \
        (unsigned)f2bf_bits(p[2 * i]) |                                        \
        ((unsigned)f2bf_bits(p[2 * i + 1]) << 16);                             \
    unsigned s0x = Wp[0], s0y = Wp[2];                                         \
    unsigned s1x = Wp[1], s1y = Wp[3];                                         \
    unsigned s2x = Wp[4], s2y = Wp[6];                                         \
    unsigned s3x = Wp[5], s3y = Wp[7];                                         \
    plswap(s0x, s0y);                                                          \
    plswap(s1x, s1y);                                                          \
    plswap(s2x, s2y);                                                          \
    plswap(s3x, s3y);                                                          \
    int4 f0, f1;                                                               \
    f0.x = (int)s0x; f0.y = (int)s1x; f0.z = (int)s0y; f0.w = (int)s1y;        \
    f1.x = (int)s2x; f1.y = (int)s3x; f1.z = (int)s2y; f1.w = (int)s3y;        \
    bf16x8 pfrag[2];                                                           \
    pfrag[0] = __builtin_bit_cast(bf16x8, f0);                                 \
    pfrag[1] = __builtin_bit_cast(bf16x8, f1);                                 \
    _Pragma("unroll") for (int db = 0; db < 4; db++)                           \
        _Pragma("unroll") for (int k2 = 0; k2 < 2; k2++) oacc[db] =            \
        __builtin_amdgcn_mfma_f32_32x32x16_bf16(vf[db][k2], pfrag[k2],         \
                                                oacc[db], 0, 0, 0);            \
  }

  const int nt = qt + 1;
  const int nt0 = nt >> 1;

  if (half) {
    for (int kb = nt0 * 32; kb < qwb; kb += 32) COMPUTE_TILE(kb, false);
    COMPUTE_TILE(qwb, true);
  } else {
    const int kend = nt0 * 32;
    for (int kb = 0; kb < kend; kb += 32) COMPUTE_TILE(kb, false);
  }
#undef COMPUTE_TILE

  if (half) {
    float* dst = Ms[w & 1][l];
#pragma unroll
    for (int db = 0; db < 4; db++)
#pragma unroll
      for (int r = 0; r < 16; r++) dst[db * 16 + r] = oacc[db][r];
    dst[64] = m;
    dst[65] = lsum;
  }
  __syncthreads();
  if (!half) {
    const float* src = Ms[w & 1][l];
    const float mB = src[64], lB = src[65];
    const float mS = fmaxf(m, mB);
    float fa = __builtin_amdgcn_exp2f(m - mS);
    float fb = __builtin_amdgcn_exp2f(mB - mS);
    const float inv = 1.0f / (lsum * fa + lB * fb);
    fa *= inv;
    fb *= inv;
    __hip_bfloat16* orow = O + (size_t)qg * (NQH * DH) + h * DH;
#pragma unroll
    for (int db = 0; db < 4; db++)
#pragma unroll
      for (int rg = 0; rg < 4; rg++) {
        ushort4 u;
        u.x = f2bf_bits(oacc[db][rg * 4 + 0] * fa + src[db * 16 + rg * 4 + 0] * fb);
        u.y = f2bf_bits(oacc[db][rg * 4 + 1] * fa + src[db * 16 + rg * 4 + 1] * fb);
        u.z = f2bf_bits(oacc[db][rg * 4 + 2] * fa + src[db * 16 + rg * 4 + 2] * fb);
        u.w = f2bf_bits(oacc[db][rg * 4 + 3] * fa + src[db * 16 + rg * 4 + 3] * fb);
        *reinterpret_cast<ushort4*>(orow + db * 32 + 8 * rg + 4 * hiP) = u;
      }
  }
}

// ---------------------------------------------------------------------------
extern "C" void kernel_launch(void* const* d_in, const int* in_sizes, int n_in,
                              void* d_out, int out_size, void* d_ws,
                              size_t ws_size, hipStream_t stream) {
  const float* hs = (const float*)d_in[0];
  const int* pos = (const int*)d_in[1];
  const float* wqkv = (const float*)d_in[2];
  const float* wo = (const float*)d_in[3];
  float* out = (float*)d_out;

  char* ws = (char*)d_ws;
  __hip_bfloat16* Xb      = (__hip_bfloat16*)(ws);                // 16 MB
  __hip_bfloat16* Wqkvb   = (__hip_bfloat16*)(ws + 16777216);     // 48 MB
  __hip_bfloat16* Wob     = (__hip_bfloat16*)(ws + 67108864);     // 32 MB
  __hip_bfloat16* QKV     = (__hip_bfloat16*)(ws + 100663296);    // 24 MB
  __hip_bfloat16* AttnOut = (__hip_bfloat16*)(ws + 125829120);    // 16 MB
  __hip_bfloat16* Kf      = (__hip_bfloat16*)(ws + 142606336);    // 4 MB
  __hip_bfloat16* Vf      = (__hip_bfloat16*)(ws);                // 4 MB (Xb dead after gemm1)

  // hs + wqkv f32->bf16 (merged)
  cvt2_kernel<<<2048, 256, 0, stream>>>(hs, Xb, wqkv, Wqkvb);

  // QKV GEMM (blocks x<24) + wo f32->bf16 on the 64 otherwise-idle CUs
  gemm_bt_kernel<true, 8, true>
      <<<dim3(32, 8), 512, 131072, stream>>>(
          Xb, Wqkvb, QKV, S_SEQ, QKV_LD, HID, 24, wo, Wob, (HID * HID) / 4);

  ropeq_kernel<<<(S_SEQ * 32 * 64) / 256, 256, 0, stream>>>(QKV, pos);
  packkv_kernel<<<2048, 256, 0, stream>>>(QKV, pos, Kf, Vf);

  attn_kernel<<<1024, 256, 0, stream>>>(QKV, Kf, Vf, AttnOut);

  gemm_bt_kernel<false, 4, false>
      <<<dim3(16, 16), 512, 98304, stream>>>(
          AttnOut, Wob, out, S_SEQ, HID, HID, 16, nullptr, nullptr, 0);
}

// Round 20
// 289.915 us; speedup vs baseline: 1.0527x; 1.0527x over previous
//
#include <hip/hip_runtime.h>
#include <hip/hip_bf16.h>
#include <cstdint>

#define S_SEQ   2048
#define HID     4096
#define NQH     32
#define NKVH    8
#define DH      128
#define QKV_LD  6144      // (32+16)*128
#define SCALE_F 0.08838834764831845f
// softmax in log2 domain: s' = s * SCALE * log2(e)
#define C2F (0.08838834764831845f * 1.4426950408889634f)

using f32x4  = __attribute__((ext_vector_type(4))) float;
using f32x16 = __attribute__((ext_vector_type(16))) float;
using bf16x8 = __attribute__((ext_vector_type(8))) __bf16;
using u32x2  = __attribute__((ext_vector_type(2))) unsigned;

#define GLOAD_LDS16(gp, lp)                                                   \
  __builtin_amdgcn_global_load_lds(                                           \
      (__attribute__((address_space(1))) const void*)(gp),                    \
      (__attribute__((address_space(3))) void*)(lp), 16, 0, 0)

__device__ __forceinline__ unsigned short f2bf_bits(float f) {
  __hip_bfloat16 b = __float2bfloat16(f);
  return __builtin_bit_cast(unsigned short, b);
}

// permlane32_swap: X[32..63] <-> Y[0..31].
__device__ __forceinline__ void plswap(unsigned& x, unsigned& y) {
  u32x2 r = __builtin_amdgcn_permlane32_swap(x, y, false, false);
  x = r[0];
  y = r[1];
}
// value of the partner lane (l ^ 32)
__device__ __forceinline__ float xhalf(float v, int hiP) {
  unsigned u = __builtin_bit_cast(unsigned, v);
  u32x2 r = __builtin_amdgcn_permlane32_swap(u, u, false, false);
  return __builtin_bit_cast(float, hiP ? r[0] : r[1]);
}

// ---------------------------------------------------------------------------
// merged f32 -> bf16 conversion for hs + wqkv (single kernel, fewer tails)
// ---------------------------------------------------------------------------
__global__ void cvt2_kernel(const float* __restrict__ hs,
                            __hip_bfloat16* __restrict__ hsb,
                            const float* __restrict__ wq,
                            __hip_bfloat16* __restrict__ wqb) {
  const int NHS = (S_SEQ * HID) / 4;     // 2,097,152 float4
  const int NWQ = (QKV_LD * HID) / 4;    // 6,291,456 float4
  int i = blockIdx.x * blockDim.x + threadIdx.x;
  int stride = gridDim.x * blockDim.x;
  for (int e = i; e < NHS + NWQ; e += stride) {
    const float4* src;
    ushort4* dst;
    int idx;
    if (e < NHS) {
      src = (const float4*)hs; dst = (ushort4*)hsb; idx = e;
    } else {
      src = (const float4*)wq; dst = (ushort4*)wqb; idx = e - NHS;
    }
    float4 v = src[idx];
    ushort4 u;
    u.x = f2bf_bits(v.x); u.y = f2bf_bits(v.y);
    u.z = f2bf_bits(v.z); u.w = f2bf_bits(v.w);
    dst[idx] = u;
  }
}

// ---------------------------------------------------------------------------
// GEMM: C[M,N] = A[M,K] * B[N,K]^T   (both bf16, B^T layout)
// Tile (MF*32) x 256, BK=64, 8 waves, 512 threads. 4-phase fine-interleaved
// schedule (ks x n-half), LDS double-buffered:
//  - per phase: {ds_read this phase's frags; issue ONE stage-group (t+1);
//    lgkmcnt(0)+sched_barrier; setprio(1) 16-MFMA cluster setprio(0);
//    [counted vmcnt at ph1/ph3]; s_barrier}
//  - A-frags held in regs across the ks's two phases: LDS reads unchanged
//  - groups g0=A-ks0, g1=B-ks0, g2=A-ks1, g3=B-ks1; uniform vmcnt(4) (MF=8)
//    / vmcnt(3) (MF=4): forces exactly the two groups the next phase needs
//  - slot swizzle (slot ^= (row>>1)&3) linear-dest + inverse-permuted source
//  - bijective XCD swizzle; column-major wgid decode (B-panel L2 sharing)
//  - FUSE: grid-x blocks >= nbx_main run the wo f32->bf16 convert
// ---------------------------------------------------------------------------
template <bool OUT_BF16, int MF, bool FUSE>
__global__ __launch_bounds__(512) void gemm_bt_kernel(
    const __hip_bfloat16* __restrict__ A, const __hip_bfloat16* __restrict__ B,
    void* __restrict__ Cv, int M, int N, int K, int nbx_main,
    const float* __restrict__ csrc, __hip_bfloat16* __restrict__ cdst,
    int cn4) {
  extern __shared__ __hip_bfloat16 sAB[];
  constexpr int A_BUF = MF * 2048;       // elements of A per buffer
  constexpr int A_KS  = MF * 1024;       // elements per k-slice of A
  constexpr int BUFSZ = A_BUF + 16384;   // + B (256 rows x 32 el) x 2 slices
  const int tid = threadIdx.x;

  if (FUSE) {
    if ((int)blockIdx.x >= nbx_main) {
      const int nb = gridDim.x - nbx_main;
      const int cid = ((int)blockIdx.x - nbx_main) + (int)blockIdx.y * nb;
      const int stride = nb * gridDim.y * 512;
      for (int e = cid * 512 + tid; e < cn4; e += stride) {
        float4 v = ((const float4*)csrc)[e];
        ushort4 u;
        u.x = f2bf_bits(v.x); u.y = f2bf_bits(v.y);
        u.z = f2bf_bits(v.z); u.w = f2bf_bits(v.w);
        ((ushort4*)cdst)[e] = u;
      }
      return;
    }
  }

  const int w = tid >> 6, l = tid & 63;
  const int wm = w >> 2, wn = w & 3;
  const int lr = l & 15;

  const int nbx = nbx_main;
  const int gdy = gridDim.y;
  const int nwg = nbx * gdy;
  int wgid = blockIdx.y * nbx + blockIdx.x;
  wgid = (wgid & 7) * (nwg >> 3) + (wgid >> 3);  // XCD chunking
  const int bx = wgid / gdy;   // column-major: chunk shares B panels
  const int by = wgid % gdy;
  const int brow = by * (MF * 32);
  const int bcol = bx * 256;

  f32x4 acc[MF][4];
#pragma unroll
  for (int m = 0; m < MF; m++)
#pragma unroll
    for (int n = 0; n < 4; n++) acc[m][n] = (f32x4){0.f, 0.f, 0.f, 0.f};

  const int r0 = tid >> 2;                                  // 0..127
  const int c0s = (((tid & 3) ^ ((tid >> 3) & 3)) << 3);    // elements
  const __hip_bfloat16* Ag = A + (size_t)(brow + r0) * K + c0s;
  const __hip_bfloat16* Bg = B + (size_t)(bcol + r0) * K + c0s;
  const int ldst = tid * 8;

  const int sw8 = (((l >> 4) ^ ((lr >> 1) & 3)) << 3);

#define STG_A(BUF, K0, KS, RB)                                                \
  GLOAD_LDS16(Ag + (K0) + (KS) * 32 + (size_t)((RB) * 128) * K,               \
              sAB + (BUF) * BUFSZ + (KS) * A_KS + (RB) * 4096 + ldst)
#define STG_B(BUF, K0, KS, RB)                                                \
  GLOAD_LDS16(Bg + (K0) + (KS) * 32 + (size_t)((RB) * 128) * K,               \
              sAB + (BUF) * BUFSZ + A_BUF + (KS) * 8192 + (RB) * 4096 + ldst)
#define STG_G0(BUF, K0)                                                       \
  {                                                                           \
    STG_A(BUF, K0, 0, 0);                                                     \
    if constexpr (MF == 8) STG_A(BUF, K0, 0, 1);                              \
  }
#define STG_G1(BUF, K0) { STG_B(BUF, K0, 0, 0); STG_B(BUF, K0, 0, 1); }
#define STG_G2(BUF, K0)                                                       \
  {                                                                           \
    STG_A(BUF, K0, 1, 0);                                                     \
    if constexpr (MF == 8) STG_A(BUF, K0, 1, 1);                              \
  }
#define STG_G3(BUF, K0) { STG_B(BUF, K0, 1, 0); STG_B(BUF, K0, 1, 1); }

#define WAIT_L()                                                              \
  {                                                                           \
    if constexpr (MF == 8)                                                    \
      asm volatile("s_waitcnt vmcnt(4)" ::: "memory");                        \
    else                                                                      \
      asm volatile("s_waitcnt vmcnt(3)" ::: "memory");                        \
  }
#define LGKM()                                                                \
  {                                                                           \
    asm volatile("s_waitcnt lgkmcnt(0)" ::: "memory");                        \
    __builtin_amdgcn_sched_barrier(0);                                        \
  }
// 16-MFMA cluster into acc[.][NH*2 + j]
#define CLUSTER(NH)                                                           \
  {                                                                           \
    __builtin_amdgcn_s_setprio(1);                                            \
    _Pragma("unroll") for (int mm = 0; mm < MF; mm++)                         \
        _Pragma("unroll") for (int j = 0; j < 2; j++)                         \
        acc[mm][(NH)*2 + j] = __builtin_amdgcn_mfma_f32_16x16x32_bf16(        \
            af[mm], bfr[j], acc[mm][(NH)*2 + j], 0, 0, 0);                    \
    __builtin_amdgcn_s_setprio(0);                                            \
  }

  const int nt = K >> 6;  // 64 K-tiles
  // prologue: all 4 groups of tile 0; wait g0,g1 (leaves g2,g3 in flight)
  STG_G0(0, 0); STG_G1(0, 0); STG_G2(0, 0); STG_G3(0, 0);
  WAIT_L();
  __builtin_amdgcn_s_barrier();

  for (int t = 0; t < nt; ++t) {
    const int buf = t & 1, nb2 = buf ^ 1;
    const int k1 = (t + 1) << 6;
    const bool hn = (t + 1) < nt;
    const __hip_bfloat16* ab = sAB + buf * BUFSZ;
    const __hip_bfloat16* bb = ab + A_BUF;
    const __hip_bfloat16* ab1 = ab + A_KS;
    const __hip_bfloat16* bb1 = bb + 8192;
    bf16x8 af[MF], bfr[2];

    // ---- ph0: ks0, n-half 0 ----
#pragma unroll
    for (int mm = 0; mm < MF; mm++)
      af[mm] = *(const bf16x8*)&ab[(wm * MF * 16 + mm * 16 + lr) * 32 + sw8];
#pragma unroll
    for (int j = 0; j < 2; j++)
      bfr[j] = *(const bf16x8*)&bb[(wn * 64 + j * 16 + lr) * 32 + sw8];
    if (hn) STG_G0(nb2, k1);
    LGKM();
    CLUSTER(0);
    __builtin_amdgcn_s_barrier();

    // ---- ph1: ks0, n-half 1 ----
#pragma unroll
    for (int j = 0; j < 2; j++)
      bfr[j] = *(const bf16x8*)&bb[(wn * 64 + (2 + j) * 16 + lr) * 32 + sw8];
    if (hn) STG_G1(nb2, k1);
    LGKM();
    CLUSTER(1);
    if (hn) {
      WAIT_L();   // forces g2,g3 of tile t (leaves g0',g1')
    } else {
      asm volatile("s_waitcnt vmcnt(0)" ::: "memory");
    }
    __builtin_amdgcn_s_barrier();

    // ---- ph2: ks1, n-half 0 ----
#pragma unroll
    for (int mm = 0; mm < MF; mm++)
      af[mm] = *(const bf16x8*)&ab1[(wm * MF * 16 + mm * 16 + lr) * 32 + sw8];
#pragma unroll
    for (int j = 0; j < 2; j++)
      bfr[j] = *(const bf16x8*)&bb1[(wn * 64 + j * 16 + lr) * 32 + sw8];
    if (hn) STG_G2(nb2, k1);
    LGKM();
    CLUSTER(0);
    __builtin_amdgcn_s_barrier();

    // ---- ph3: ks1, n-half 1 ----
#pragma unroll
    for (int j = 0; j < 2; j++)
      bfr[j] = *(const bf16x8*)&bb1[(wn * 64 + (2 + j) * 16 + lr) * 32 + sw8];
    if (hn) STG_G3(nb2, k1);
    LGKM();
    CLUSTER(1);
    if (hn) {
      WAIT_L();   // forces g0',g1' of tile t+1 (leaves g2',g3')
    }
    __builtin_amdgcn_s_barrier();
  }
#undef STG_A
#undef STG_B
#undef STG_G0
#undef STG_G1
#undef STG_G2
#undef STG_G3
#undef WAIT_L
#undef LGKM
#undef CLUSTER

  const int jr = (l >> 4) << 2;
  if (OUT_BF16) {
    __hip_bfloat16* C = (__hip_bfloat16*)Cv;
#pragma unroll
    for (int m = 0; m < MF; m++)
#pragma unroll
      for (int n = 0; n < 4; n++)
#pragma unroll
        for (int j = 0; j < 4; j++) {
          size_t row = brow + wm * MF * 16 + m * 16 + jr + j;
          size_t col = bcol + wn * 64 + n * 16 + lr;
          C[row * N + col] = __float2bfloat16(acc[m][n][j]);
        }
  } else {
    float* C = (float*)Cv;
#pragma unroll
    for (int m = 0; m < MF; m++)
#pragma unroll
      for (int n = 0; n < 4; n++)
#pragma unroll
        for (int j = 0; j < 4; j++) {
          size_t row = brow + wm * MF * 16 + m * 16 + jr + j;
          size_t col = bcol + wn * 64 + n * 16 + lr;
          C[row * N + col] = acc[m][n][j];
        }
  }
}

// ---------------------------------------------------------------------------
// RoPE (neox) in-place on Q only (heads 0..31); K rope fused into packkv.
// ---------------------------------------------------------------------------
__global__ void ropeq_kernel(__hip_bfloat16* __restrict__ QKV,
                             const int* __restrict__ pos) {
  int idx = blockIdx.x * blockDim.x + threadIdx.x;  // S*32*64 total
  int d = idx & 63;
  int head = (idx >> 6) & 31;
  int s = idx >> 11;
  float p = (float)pos[s];
  float inv = exp2f(-(float)d * 0.2076205059304297f);
  float fr = p * inv;
  float sn, cs;
  sincosf(fr, &sn, &cs);
  size_t base = (size_t)s * QKV_LD + head * 128 + d;
  float x1 = __bfloat162float(QKV[base]);
  float x2 = __bfloat162float(QKV[base + 64]);
  QKV[base]      = __float2bfloat16(x1 * cs - x2 * sn);
  QKV[base + 64] = __float2bfloat16(x2 * cs + x1 * sn);
}

// ---------------------------------------------------------------------------
// Pack K (with fused rope) and V into fragment-ordered buffers for attn.
// ---------------------------------------------------------------------------
__global__ void packkv_kernel(const __hip_bfloat16* __restrict__ QKV,
                              const int* __restrict__ pos,
                              __hip_bfloat16* __restrict__ Kf,
                              __hip_bfloat16* __restrict__ Vf) {
  int o = blockIdx.x * blockDim.x + threadIdx.x;  // 2 * 2^18 chunks
  const int lane = o & 63;
  const int slot = (o >> 6) & 7;
  const int t    = (o >> 9) & 63;
  const int kvh  = (o >> 15) & 7;
  const int off8 = (o & 0x3FFFF) * 8;
  if (o < (1 << 18)) {
    const int s  = t * 32 + (lane & 31);
    const int d0 = slot * 16 + (lane >> 5) * 8;
    const __hip_bfloat16* kb = QKV + (size_t)s * QKV_LD + 4096 + kvh * DH;
    bf16x8 own = *(const bf16x8*)(kb + d0);
    bf16x8 prt = *(const bf16x8*)(kb + (d0 ^ 64));
    float p = (float)pos[s];
    bf16x8 outv;
#pragma unroll
    for (int j = 0; j < 8; j++) {
      float f = (float)((d0 & 63) + j);
      float inv = exp2f(-f * 0.2076205059304297f);
      float sn, cs;
      sincosf(p * inv, &sn, &cs);
      float a = (float)own[j], b = (float)prt[j];
      outv[j] = (__bf16)((d0 < 64) ? (a * cs - b * sn) : (a * cs + b * sn));
    }
    *(bf16x8*)(Kf + off8) = outv;
  } else {
    const int s0 = t * 32 + (slot & 1) * 16 + (lane >> 5) * 8;
    const int d  = (slot >> 1) * 32 + (lane & 31);
    const __hip_bfloat16* src = QKV + (size_t)s0 * QKV_LD + 5120 + kvh * DH + d;
    ushort4 a, b;
    a.x = __builtin_bit_cast(unsigned short, src[0 * QKV_LD]);
    a.y = __builtin_bit_cast(unsigned short, src[1 * QKV_LD]);
    a.z = __builtin_bit_cast(unsigned short, src[2 * QKV_LD]);
    a.w = __builtin_bit_cast(unsigned short, src[3 * QKV_LD]);
    b.x = __builtin_bit_cast(unsigned short, src[4 * QKV_LD]);
    b.y = __builtin_bit_cast(unsigned short, src[5 * QKV_LD]);
    b.z = __builtin_bit_cast(unsigned short, src[6 * QKV_LD]);
    b.w = __builtin_bit_cast(unsigned short, src[7 * QKV_LD]);
    *(ushort4*)(Vf + off8)     = a;
    *(ushort4*)(Vf + off8 + 4) = b;
  }
}

// ---------------------------------------------------------------------------
// Causal GQA flash attention (unchanged): swapped-QK 32x32 + split-KV x2.
// ---------------------------------------------------------------------------
__global__ __launch_bounds__(256, 2) void attn_kernel(
    const __hip_bfloat16* __restrict__ QKV, const __hip_bfloat16* __restrict__ Kf,
    const __hip_bfloat16* __restrict__ Vf, __hip_bfloat16* __restrict__ O) {
  __shared__ float Ms[2][64][67];
  const int tid = threadIdx.x;
  const int w = tid >> 6, l = tid & 63;
  const int l31 = l & 31;
  const int hiP = l >> 5;
  const int bid = blockIdx.x;
  const int kvh = bid & 7;
  const int hp = (bid >> 3) & 1;
  const int qt = 63 - (bid >> 4);
  const int half = w >> 1;
  const int h = kvh * 4 + hp * 2 + (w & 1);
  const int qwb = qt * 32;
  const int qg = qwb + l31;

  const __hip_bfloat16* Qp  = QKV + (size_t)h * DH;
  const __hip_bfloat16* Kfp = Kf + (size_t)kvh * 262144 + l * 8;
  const __hip_bfloat16* Vfp = Vf + (size_t)kvh * 262144 + l * 8;

  bf16x8 qf[8];
  {
    const __hip_bfloat16* qrow = Qp + (size_t)(qwb + l31) * QKV_LD + hiP * 8;
#pragma unroll
    for (int ks = 0; ks < 8; ks++) qf[ks] = *(const bf16x8*)(qrow + ks * 16);
  }

  f32x16 oacc[4];
#pragma unroll
  for (int db = 0; db < 4; db++)
#pragma unroll
    for (int r = 0; r < 16; r++) oacc[db][r] = 0.f;
  float m = -1e30f, lsum = 0.f;

#define COMPUTE_TILE(KB, MASKED)                                               \
  {                                                                            \
    const int kb_ = (KB);                                                      \
    const int toff_ = (kb_ >> 5) * 4096;                                       \
    f32x16 sacc;                                                               \
    _Pragma("unroll") for (int r = 0; r < 16; r++) sacc[r] = 0.f;              \
    {                                                                          \
      bf16x8 kf[8];                                                            \
      _Pragma("unroll") for (int ks = 0; ks < 8; ks++) kf[ks] =                \
          *(const bf16x8*)(Kfp + toff_ + ks * 512);                            \
      _Pragma("unroll") for (int ks = 0; ks < 8; ks++) sacc =                  \
          __builtin_amdgcn_mfma_f32_32x32x16_bf16(kf[ks], qf[ks], sacc, 0, 0,  \
                                                  0);                          \
    }                                                                          \
    bf16x8 vf[4][2];                                                           \
    _Pragma("unroll") for (int db = 0; db < 4; db++)                           \
        _Pragma("unroll") for (int k2 = 0; k2 < 2; k2++) vf[db][k2] =          \
        *(const bf16x8*)(Vfp + toff_ + (db * 2 + k2) * 512);                   \
    float s[16];                                                               \
    _Pragma("unroll") for (int r = 0; r < 16; r++) s[r] = sacc[r] * C2F;       \
    if (MASKED) {                                                              \
      _Pragma("unroll") for (int r = 0; r < 16; r++) {                         \
        const int kvg = kb_ + (r & 3) + 8 * (r >> 2) + 4 * hiP;                \
        s[r] = (kvg <= qg) ? s[r] : -1e30f;                                    \
      }                                                                        \
    }                                                                          \
    float m0 = fmaxf(fmaxf(s[0], s[1]), fmaxf(s[2], s[3]));                    \
    float m1 = fmaxf(fmaxf(s[4], s[5]), fmaxf(s[6], s[7]));                    \
    float m2 = fmaxf(fmaxf(s[8], s[9]), fmaxf(s[10], s[11]));                  \
    float m3 = fmaxf(fmaxf(s[12], s[13]), fmaxf(s[14], s[15]));                \
    float rmax = fmaxf(fmaxf(m0, m1), fmaxf(m2, m3));                          \
    rmax = fmaxf(rmax, xhalf(rmax, hiP));                                      \
    if (__any(rmax - m > 8.0f)) {                                              \
      float mn = fmaxf(m, rmax);                                               \
      float sc = __builtin_amdgcn_exp2f(m - mn);                               \
      lsum *= sc;                                                              \
      _Pragma("unroll") for (int db = 0; db < 4; db++)                         \
          _Pragma("unroll") for (int r = 0; r < 16; r++) oacc[db][r] *= sc;    \
      m = mn;                                                                  \
    }                                                                          \
    float p[16];                                                               \
    _Pragma("unroll") for (int r = 0; r < 16; r++) p[r] =                      \
        __builtin_amdgcn_exp2f(s[r] - m);                                      \
    float rs = ((p[0] + p[1]) + (p[2] + p[3])) +                               \
               ((p[4] + p[5]) + (p[6] + p[7])) +                               \
               ((p[8] + p[9]) + (p[10] + p[11])) +                             \
               ((p[12] + p[13]) + (p[14] + p[15]));                            \
    lsum += rs + xhalf(rs, hiP);                                               \
    unsigned Wp[8];                                                            \
    _Pragma("unroll") for (int i = 0; i < 8; i++) Wp[i] =                      \
        (unsigned)f2bf_bits(p[2 * i]) |                                        \
        ((unsigned)f2bf_bits(p[2 * i + 1]) << 16);                             \
    unsigned s0x = Wp[0], s0y = Wp[2];                                         \
    unsigned s1x = Wp[1], s1y = Wp[3];                                         \
    unsigned s2x = Wp[4], s2y = Wp[6];                                         \
    unsigned s3x = Wp[5], s3y = Wp[7];                                         \
    plswap(s0x, s0y);                                                          \
    plswap(s1x, s1y);                                                          \
    plswap(s2x, s2y);                                                          \
    plswap(s3x, s3y);                                                          \
    int4 f0, f1;                                                               \
    f0.x = (int)s0x; f0.y = (int)s1x; f0.z = (int)s0y; f0.w = (int)s1y;        \
    f1.x = (int)s2x; f1.y = (int)s3x; f1.z = (int)s2y; f1.w = (int)s3y;        \
    bf16x8 pfrag[2];                                                           \
    pfrag[0] = __builtin_bit_cast(bf16x8, f0);                                 \
    pfrag[1] = __builtin_bit_cast(bf16x8, f1);                                 \
    _Pragma("unroll") for (int db = 0; db < 4; db++)                           \
        _Pragma("unroll") for (int k2 = 0; k2 < 2; k2++) oacc[db] =            \
        __builtin_amdgcn_mfma_f32_32x32x16_bf16(vf[db][k2], pfrag[k2],         \
                                                oacc[db], 0, 0, 0);            \
  }

  const int nt = qt + 1;
  const int nt0 = nt >> 1;

  if (half) {
    for (int kb = nt0 * 32; kb < qwb; kb += 32) COMPUTE_TILE(kb, false);
    COMPUTE_TILE(qwb, true);
  } else {
    const int kend = nt0 * 32;
    for (int kb = 0; kb < kend; kb += 32) COMPUTE_TILE(kb, false);
  }
#undef COMPUTE_TILE

  if (half) {
    float* dst = Ms[w & 1][l];
#pragma unroll
    for (int db = 0; db < 4; db++)
#pragma unroll
      for (int r = 0; r < 16; r++) dst[db * 16 + r] = oacc[db][r];
    dst[64] = m;
    dst[65] = lsum;
  }
  __syncthreads();
  if (!half) {
    const float* src = Ms[w & 1][l];
    const float mB = src[64], lB = src[65];
    const float mS = fmaxf(m, mB);
    float fa = __builtin_amdgcn_exp2f(m - mS);
    float fb = __builtin_amdgcn_exp2f(mB - mS);
    const float inv = 1.0f / (lsum * fa + lB * fb);
    fa *= inv;
    fb *= inv;
    __hip_bfloat16* orow = O + (size_t)qg * (NQH * DH) + h * DH;
#pragma unroll
    for (int db = 0; db < 4; db++)
#pragma unroll
      for (int rg = 0; rg < 4; rg++) {
        ushort4 u;
        u.x = f2bf_bits(oacc[db][rg * 4 + 0] * fa + src[db * 16 + rg * 4 + 0] * fb);
        u.y = f2bf_bits(oacc[db][rg * 4 + 1] * fa + src[db * 16 + rg * 4 + 1] * fb);
        u.z = f2bf_bits(oacc[db][rg * 4 + 2] * fa + src[db * 16 + rg * 4 + 2] * fb);
        u.w = f2bf_bits(oacc[db][rg * 4 + 3] * fa + src[db * 16 + rg * 4 + 3] * fb);
        *reinterpret_cast<ushort4*>(orow + db * 32 + 8 * rg + 4 * hiP) = u;
      }
  }
}

// ---------------------------------------------------------------------------
extern "C" void kernel_launch(void* const* d_in, const int* in_sizes, int n_in,
                              void* d_out, int out_size, void* d_ws,
                              size_t ws_size, hipStream_t stream) {
  const float* hs = (const float*)d_in[0];
  const int* pos = (const int*)d_in[1];
  const float* wqkv = (const float*)d_in[2];
  const float* wo = (const float*)d_in[3];
  float* out = (float*)d_out;

  char* ws = (char*)d_ws;
  __hip_bfloat16* Xb      = (__hip_bfloat16*)(ws);                // 16 MB
  __hip_bfloat16* Wqkvb   = (__hip_bfloat16*)(ws + 16777216);     // 48 MB
  __hip_bfloat16* Wob     = (__hip_bfloat16*)(ws + 67108864);     // 32 MB
  __hip_bfloat16* QKV     = (__hip_bfloat16*)(ws + 100663296);    // 24 MB
  __hip_bfloat16* AttnOut = (__hip_bfloat16*)(ws + 125829120);    // 16 MB
  __hip_bfloat16* Kf      = (__hip_bfloat16*)(ws + 142606336);    // 4 MB
  __hip_bfloat16* Vf      = (__hip_bfloat16*)(ws);                // 4 MB (Xb dead after gemm1)

  // hs + wqkv f32->bf16 (merged)
  cvt2_kernel<<<2048, 256, 0, stream>>>(hs, Xb, wqkv, Wqkvb);

  // QKV GEMM (blocks x<24) + wo f32->bf16 on the 64 otherwise-idle CUs
  gemm_bt_kernel<true, 8, true>
      <<<dim3(32, 8), 512, 131072, stream>>>(
          Xb, Wqkvb, QKV, S_SEQ, QKV_LD, HID, 24, wo, Wob, (HID * HID) / 4);

  ropeq_kernel<<<(S_SEQ * 32 * 64) / 256, 256, 0, stream>>>(QKV, pos);
  packkv_kernel<<<2048, 256, 0, stream>>>(QKV, pos, Kf, Vf);

  attn_kernel<<<1024, 256, 0, stream>>>(QKV, Kf, Vf, AttnOut);

  gemm_bt_kernel<false, 4, false>
      <<<dim3(16, 16), 512, 98304, stream>>>(
          AttnOut, Wob, out, S_SEQ, HID, HID, 16, nullptr, nullptr, 0);
}